// Round 3
// baseline (684.634 us; speedup 1.0000x reference)
//
#include <hip/hip_runtime.h>
#include <hip/hip_bf16.h>
#include <cstdint>

typedef unsigned short u16;
typedef __attribute__((ext_vector_type(8))) __bf16 bf16x8;
typedef __attribute__((ext_vector_type(4))) float f32x4;

#define N_NODES 131072
#define C 64
#define KNB 27
#define BATCH 8
#define EMB 512
#define NGROUP 32
#define GN_EPS 1e-5f

__device__ __forceinline__ float silu_f(float x) {
    return x / (1.0f + __expf(-x));
}

__device__ __forceinline__ u16 f2bf(float x) {
    __hip_bfloat16 h = __float2bfloat16(x);
    return __builtin_bit_cast(u16, h);
}

__device__ __forceinline__ float bf2f(u16 h) {
    unsigned u = ((unsigned)h) << 16;
    return __builtin_bit_cast(float, u);
}

__device__ __forceinline__ unsigned pack2(float a, float b) {
    return (unsigned)f2bf(a) | ((unsigned)f2bf(b) << 16);
}

// ============ setup: W-prep (216 blk) + time_mlp (8 blk) + gn1 stats (512 blk) ============
__global__ void setup_kernel(const float* __restrict__ W1, const float* __restrict__ W2,
                             u16* __restrict__ Wb1, u16* __restrict__ Wb2,
                             const float* __restrict__ te, const float* __restrict__ Wt,
                             const float* __restrict__ bt, float* __restrict__ tvec,
                             const float* __restrict__ x, const int* __restrict__ batch_id,
                             float* __restrict__ stats, float* __restrict__ cnt) {
    __shared__ float sh[520];
    const int bid = blockIdx.x;
    const int t = threadIdx.x;
    if (bid < 216) {
        // W fp32 [k][ci][co] -> bf16 [k][co][ci]
        const int per = KNB * C * C; // 110592
        int e0 = (bid * 256 + t) * 4;
#pragma unroll
        for (int d = 0; d < 4; ++d) {
            int idx = e0 + d;
            const float* src = (idx < per) ? W1 : W2;
            u16* dst = (idx < per) ? Wb1 : Wb2;
            int e = (idx < per) ? idx : idx - per;
            int k = e >> 12;
            int rem = e & 4095;
            int co = rem >> 6;
            int ci = rem & 63;
            dst[e] = f2bf(src[(k * C + ci) * C + co]);
        }
    } else if (bid < 224) {
        int b = bid - 216;
        int co = t & 63, seg = t >> 6;
        float acc = 0.f;
        for (int i = 0; i < 128; ++i) {
            int e = seg * 128 + i;
            float v = te[b * EMB + e];
            acc += silu_f(v) * Wt[e * C + co];
        }
        sh[t] = acc;
        __syncthreads();
        if (t < 64) tvec[b * C + t] = sh[t] + sh[t + 64] + sh[t + 128] + sh[t + 192] + bt[t];
    } else {
        // gn1 stats over x: 256 nodes per block
        for (int i = t; i < 520; i += 256) sh[i] = 0.f;
        __syncthreads();
        const int n0 = (bid - 224) * 256;
        const int c4 = t & 15, r = t >> 4;
        float s0 = 0.f, ss0 = 0.f, s1 = 0.f, ss1 = 0.f, c = 0.f;
        int cur = -1;
        for (int i = 0; i < 16; ++i) {
            int n = n0 + i * 16 + r;
            int b = batch_id[n];
            if (b != cur) {
                if (cur >= 0) {
                    int g0 = 2 * c4;
                    atomicAdd(&sh[(cur * NGROUP + g0) * 2 + 0], s0);
                    atomicAdd(&sh[(cur * NGROUP + g0) * 2 + 1], ss0);
                    atomicAdd(&sh[(cur * NGROUP + g0 + 1) * 2 + 0], s1);
                    atomicAdd(&sh[(cur * NGROUP + g0 + 1) * 2 + 1], ss1);
                    if (c4 == 0) atomicAdd(&sh[512 + cur], c);
                }
                cur = b; s0 = ss0 = s1 = ss1 = c = 0.f;
            }
            float4 v = *(const float4*)(x + (size_t)n * C + c4 * 4);
            s0 += v.x + v.y;  ss0 += v.x * v.x + v.y * v.y;
            s1 += v.z + v.w;  ss1 += v.z * v.z + v.w * v.w;
            c += 1.f;
        }
        {
            int g0 = 2 * c4;
            atomicAdd(&sh[(cur * NGROUP + g0) * 2 + 0], s0);
            atomicAdd(&sh[(cur * NGROUP + g0) * 2 + 1], ss0);
            atomicAdd(&sh[(cur * NGROUP + g0 + 1) * 2 + 0], s1);
            atomicAdd(&sh[(cur * NGROUP + g0 + 1) * 2 + 1], ss1);
            if (c4 == 0) atomicAdd(&sh[512 + cur], c);
        }
        __syncthreads();
        for (int i = t; i < 512; i += 256)
            if (sh[i] != 0.f) atomicAdd(&stats[i], sh[i]);
        if (t < 8 && sh[512 + t] != 0.f) atomicAdd(&cnt[t], sh[512 + t]);
    }
}

// ============ normalize + affine + SiLU -> bf16 (fp32 input), 8 ch/thread ============
__global__ void gn_apply_f32(const float* __restrict__ x, const int* __restrict__ batch_id,
                             const float* __restrict__ stats, const float* __restrict__ cnt,
                             const float* __restrict__ gamma, const float* __restrict__ beta,
                             u16* __restrict__ out) {
    int idx = blockIdx.x * 256 + threadIdx.x; // N*8
    int n = idx >> 3, seg = idx & 7;
    int b = batch_id[n];
    float denom = cnt[b] * 2.0f;
    float4 v0 = *(const float4*)(x + (size_t)n * C + seg * 8);
    float4 v1 = *(const float4*)(x + (size_t)n * C + seg * 8 + 4);
    float4 ga0 = *(const float4*)(gamma + seg * 8);
    float4 ga1 = *(const float4*)(gamma + seg * 8 + 4);
    float4 be0 = *(const float4*)(beta + seg * 8);
    float4 be1 = *(const float4*)(beta + seg * 8 + 4);
    float mn[4], rs[4];
#pragma unroll
    for (int p = 0; p < 4; ++p) {
        float2 st = *(const float2*)(stats + (b * NGROUP + seg * 4 + p) * 2);
        float mean = st.x / denom;
        float var = st.y / denom - mean * mean;
        mn[p] = mean;
        rs[p] = rsqrtf(var + GN_EPS);
    }
    float y0 = silu_f((v0.x - mn[0]) * rs[0] * ga0.x + be0.x);
    float y1 = silu_f((v0.y - mn[0]) * rs[0] * ga0.y + be0.y);
    float y2 = silu_f((v0.z - mn[1]) * rs[1] * ga0.z + be0.z);
    float y3 = silu_f((v0.w - mn[1]) * rs[1] * ga0.w + be0.w);
    float y4 = silu_f((v1.x - mn[2]) * rs[2] * ga1.x + be1.x);
    float y5 = silu_f((v1.y - mn[2]) * rs[2] * ga1.y + be1.y);
    float y6 = silu_f((v1.z - mn[3]) * rs[3] * ga1.z + be1.z);
    float y7 = silu_f((v1.w - mn[3]) * rs[3] * ga1.w + be1.w);
    uint4 o;
    o.x = pack2(y0, y1); o.y = pack2(y2, y3); o.z = pack2(y4, y5); o.w = pack2(y6, y7);
    *(uint4*)(out + (size_t)n * C + seg * 8) = o;
}

// ============ normalize + affine + SiLU -> bf16 (bf16 input), 8 ch/thread ============
__global__ void gn_apply_bf16(const u16* __restrict__ x, const int* __restrict__ batch_id,
                              const float* __restrict__ stats, const float* __restrict__ cnt,
                              const float* __restrict__ gamma, const float* __restrict__ beta,
                              u16* __restrict__ out) {
    int idx = blockIdx.x * 256 + threadIdx.x;
    int n = idx >> 3, seg = idx & 7;
    int b = batch_id[n];
    float denom = cnt[b] * 2.0f;
    uint4 u = *(const uint4*)(x + (size_t)n * C + seg * 8);
    float4 ga0 = *(const float4*)(gamma + seg * 8);
    float4 ga1 = *(const float4*)(gamma + seg * 8 + 4);
    float4 be0 = *(const float4*)(beta + seg * 8);
    float4 be1 = *(const float4*)(beta + seg * 8 + 4);
    float mn[4], rs[4];
#pragma unroll
    for (int p = 0; p < 4; ++p) {
        float2 st = *(const float2*)(stats + (b * NGROUP + seg * 4 + p) * 2);
        float mean = st.x / denom;
        float var = st.y / denom - mean * mean;
        mn[p] = mean;
        rs[p] = rsqrtf(var + GN_EPS);
    }
    float v0 = bf2f(u.x & 0xffff), v1 = bf2f(u.x >> 16);
    float v2 = bf2f(u.y & 0xffff), v3 = bf2f(u.y >> 16);
    float v4 = bf2f(u.z & 0xffff), v5 = bf2f(u.z >> 16);
    float v6 = bf2f(u.w & 0xffff), v7 = bf2f(u.w >> 16);
    float y0 = silu_f((v0 - mn[0]) * rs[0] * ga0.x + be0.x);
    float y1 = silu_f((v1 - mn[0]) * rs[0] * ga0.y + be0.y);
    float y2 = silu_f((v2 - mn[1]) * rs[1] * ga0.z + be0.z);
    float y3 = silu_f((v3 - mn[1]) * rs[1] * ga0.w + be0.w);
    float y4 = silu_f((v4 - mn[2]) * rs[2] * ga1.x + be1.x);
    float y5 = silu_f((v5 - mn[2]) * rs[2] * ga1.y + be1.y);
    float y6 = silu_f((v6 - mn[3]) * rs[3] * ga1.z + be1.z);
    float y7 = silu_f((v7 - mn[3]) * rs[3] * ga1.w + be1.w);
    uint4 o;
    o.x = pack2(y0, y1); o.y = pack2(y2, y3); o.z = pack2(y4, y5); o.w = pack2(y6, y7);
    *(uint4*)(out + (size_t)n * C + seg * 8) = o;
}

// ============ gather conv: barrier-free, LDS-free, W from global (L2-warm) ============
// Wave tile: 16 nodes x 64 co. Block 256 thr = 4 waves = 64 nodes. Grid 2048.
// conv1: ADD_T + FUSE_STATS (gn2 stats from register-resident fp32 output), h2 bf16.
// conv2: residual add, fp32 out.
template <bool ADD_T, bool FUSE_STATS, bool OUT_F32_RES>
__global__ __launch_bounds__(256, 6) void conv_kernel(
    const u16* __restrict__ act, const int* __restrict__ neigh,
    const u16* __restrict__ Wb, const float* __restrict__ bias,
    const float* __restrict__ tvec, const int* __restrict__ batch_id,
    const float* __restrict__ resid, void* __restrict__ outp,
    float* __restrict__ stats, float* __restrict__ cnt) {
    __shared__ float shs[520];

    const int tid = threadIdx.x;
    const int w = tid >> 6, lane = tid & 63;
    const int q = lane >> 4, m = lane & 15;
    const int n0 = blockIdx.x * 64;
    const int nw = n0 + w * 16;

    if (FUSE_STATS) {
        for (int i = tid; i < 520; i += 256) shs[i] = 0.f;
    }

    const int* nptr = neigh + (size_t)(nw + m) * KNB;
    const u16* alane = act + q * 8;          // + row_off (+0 / +32)
    const u16* wlane = Wb + m * 64 + q * 8;  // + k*4096 + j*1024 + kk*32

    f32x4 acc[4] = {};
    bf16x8 a0, a1;
    int offn;

    {
        int off0 = nptr[0] * C;
        a0 = *(const bf16x8*)(alane + off0);
        a1 = *(const bf16x8*)(alane + off0 + 32);
        offn = nptr[1] * C;
    }

    for (int k = 0; k < KNB; ++k) {
        bf16x8 an0, an1;
        if (k < KNB - 1) {
            an0 = *(const bf16x8*)(alane + offn);
            an1 = *(const bf16x8*)(alane + offn + 32);
        }
        if (k < KNB - 2) offn = nptr[k + 2] * C;
        const u16* wk = wlane + k * 4096;
#pragma unroll
        for (int j = 0; j < 4; ++j) {
            bf16x8 b0 = *(const bf16x8*)(wk + j * 1024);
            bf16x8 b1 = *(const bf16x8*)(wk + j * 1024 + 32);
            acc[j] = __builtin_amdgcn_mfma_f32_16x16x32_bf16(a0, b0, acc[j], 0, 0, 0);
            acc[j] = __builtin_amdgcn_mfma_f32_16x16x32_bf16(a1, b1, acc[j], 0, 0, 0);
        }
        if (k < KNB - 1) { a0 = an0; a1 = an1; }
    }

    // ---- epilogue: bias (+temb), store; D: col=m (co j*16+m), row=q*4+reg (node) ----
    float bs[4];
#pragma unroll
    for (int j = 0; j < 4; ++j) bs[j] = bias[j * 16 + m];

    float vout[4][4]; // [reg][j]
#pragma unroll
    for (int reg = 0; reg < 4; ++reg) {
        const int n = nw + q * 4 + reg;
        int b = 0;
        if (ADD_T) b = batch_id[n];
#pragma unroll
        for (int j = 0; j < 4; ++j) {
            const int co = j * 16 + m;
            float v = acc[j][reg] + bs[j];
            if (ADD_T) v += tvec[b * C + co];
            vout[reg][j] = v;
            if (OUT_F32_RES) {
                ((float*)outp)[(size_t)n * C + co] = v + resid[(size_t)n * C + co];
            } else {
                ((u16*)outp)[(size_t)n * C + co] = f2bf(v);
            }
        }
    }

    if (FUSE_STATS) {
        __syncthreads(); // shs zero complete (and all waves at epilogue)
        const int blo = batch_id[nw], bhi = batch_id[nw + 15];
        if (blo == bhi) {
            // fast path: wave's 16 nodes share batch blo
#pragma unroll
            for (int j = 0; j < 4; ++j) {
                float s = vout[0][j] + vout[1][j] + vout[2][j] + vout[3][j];
                float ss = vout[0][j] * vout[0][j] + vout[1][j] * vout[1][j] +
                           vout[2][j] * vout[2][j] + vout[3][j] * vout[3][j];
                s += __shfl_xor(s, 16, 64);  ss += __shfl_xor(ss, 16, 64);
                s += __shfl_xor(s, 32, 64);  ss += __shfl_xor(ss, 32, 64);
                s += __shfl_xor(s, 1, 64);   ss += __shfl_xor(ss, 1, 64);
                if (q == 0 && (m & 1) == 0) {
                    int g = (j * 16 + m) >> 1;
                    atomicAdd(&shs[(blo * NGROUP + g) * 2 + 0], s);
                    atomicAdd(&shs[(blo * NGROUP + g) * 2 + 1], ss);
                }
            }
        } else {
            // slow path (batch boundary inside wave): per-value
#pragma unroll
            for (int reg = 0; reg < 4; ++reg) {
                int b = batch_id[nw + q * 4 + reg];
#pragma unroll
                for (int j = 0; j < 4; ++j) {
                    int g = (j * 16 + m) >> 1;
                    float v = vout[reg][j];
                    atomicAdd(&shs[(b * NGROUP + g) * 2 + 0], v);
                    atomicAdd(&shs[(b * NGROUP + g) * 2 + 1], v * v);
                }
            }
        }
        if (tid < 64) atomicAdd(&shs[512 + batch_id[n0 + tid]], 1.0f);
        __syncthreads();
        for (int i = tid; i < 512; i += 256)
            if (shs[i] != 0.f) atomicAdd(&stats[i], shs[i]);
        if (tid < 8 && shs[512 + tid] != 0.f) atomicAdd(&cnt[tid], shs[512 + tid]);
    }
}

extern "C" void kernel_launch(void* const* d_in, const int* in_sizes, int n_in,
                              void* d_out, int out_size, void* d_ws, size_t ws_size,
                              hipStream_t stream) {
    const float* x        = (const float*)d_in[0];
    const float* time_emb = (const float*)d_in[1];
    const int*   batch_id = (const int*)d_in[2];
    const int*   neigh    = (const int*)d_in[3];
    const float* g1       = (const float*)d_in[4];
    const float* be1      = (const float*)d_in[5];
    const float* W1       = (const float*)d_in[6];
    const float* b1       = (const float*)d_in[7];
    const float* Wt       = (const float*)d_in[8];
    const float* bt       = (const float*)d_in[9];
    const float* g2       = (const float*)d_in[10];
    const float* be2      = (const float*)d_in[11];
    const float* W2       = (const float*)d_in[12];
    const float* b2       = (const float*)d_in[13];

    char* ws = (char*)d_ws;
    u16*   h1     = (u16*)(ws + 0);            // 16 MB
    u16*   h2     = (u16*)(ws + 16777216);     // 16 MB
    u16*   h3     = (u16*)(ws + 33554432);     // 16 MB
    u16*   Wb1    = (u16*)(ws + 50331648);     // 221184 B
    u16*   Wb2    = (u16*)(ws + 50552832);     // 221184 B
    float* tvec   = (float*)(ws + 50774016);   // 2048 B
    float* stats1 = (float*)(ws + 50776064);   // 512 f
    float* cnt1   = stats1 + 512;              // 8 f
    float* stats2 = cnt1 + 8;                  // 512 f
    float* cnt2   = stats2 + 512;              // 8 f

    hipMemsetAsync(ws + 50776064, 0, 1040 * sizeof(float), stream);
    setup_kernel<<<736, 256, 0, stream>>>(W1, W2, Wb1, Wb2, time_emb, Wt, bt, tvec,
                                          x, batch_id, stats1, cnt1);
    gn_apply_f32<<<4096, 256, 0, stream>>>(x, batch_id, stats1, cnt1, g1, be1, h1);
    conv_kernel<true, true, false><<<2048, 256, 0, stream>>>(
        h1, neigh, Wb1, b1, tvec, batch_id, nullptr, (void*)h2, stats2, cnt2);
    gn_apply_bf16<<<4096, 256, 0, stream>>>(h2, batch_id, stats2, cnt2, g2, be2, h3);
    conv_kernel<false, false, true><<<2048, 256, 0, stream>>>(
        h3, neigh, Wb2, b2, nullptr, nullptr, x, (void*)d_out, nullptr, nullptr);
}

// Round 4
// 302.618 us; speedup vs baseline: 2.2624x; 2.2624x over previous
//
#include <hip/hip_runtime.h>
#include <hip/hip_bf16.h>
#include <cstdint>

typedef unsigned short u16;
typedef __attribute__((ext_vector_type(8))) __bf16 bf16x8;
typedef __attribute__((ext_vector_type(4))) float f32x4;

#define N_NODES 131072
#define C 64
#define KNB 27
#define BATCH 8
#define EMB 512
#define NGROUP 32
#define GN_EPS 1e-5f

__device__ __forceinline__ void gload_lds16(const void* gsrc, void* ldsdst) {
    __builtin_amdgcn_global_load_lds(
        (const __attribute__((address_space(1))) char*)(unsigned long long)(uintptr_t)gsrc,
        (__attribute__((address_space(3))) char*)(unsigned int)(uintptr_t)ldsdst,
        16, 0, 0);
}

__device__ __forceinline__ float silu_f(float x) {
    return x / (1.0f + __expf(-x));
}

__device__ __forceinline__ u16 f2bf(float x) {
    __hip_bfloat16 h = __float2bfloat16(x);
    return __builtin_bit_cast(u16, h);
}

__device__ __forceinline__ float bf2f(u16 h) {
    unsigned u = ((unsigned)h) << 16;
    return __builtin_bit_cast(float, u);
}

__device__ __forceinline__ unsigned pack2(float a, float b) {
    return (unsigned)f2bf(a) | ((unsigned)f2bf(b) << 16);
}

// ============ setup: W-prep (216 blk) + time_mlp (8 blk) + gn1 stats (512 blk) ============
__global__ void setup_kernel(const float* __restrict__ W1, const float* __restrict__ W2,
                             u16* __restrict__ Wb1, u16* __restrict__ Wb2,
                             const float* __restrict__ te, const float* __restrict__ Wt,
                             const float* __restrict__ bt, float* __restrict__ tvec,
                             const float* __restrict__ x, const int* __restrict__ batch_id,
                             float* __restrict__ stats, float* __restrict__ cnt) {
    __shared__ float sh[520];
    const int bid = blockIdx.x;
    const int t = threadIdx.x;
    if (bid < 216) {
        const int per = KNB * C * C; // 110592
        int e0 = (bid * 256 + t) * 4;
#pragma unroll
        for (int d = 0; d < 4; ++d) {
            int idx = e0 + d;
            const float* src = (idx < per) ? W1 : W2;
            u16* dst = (idx < per) ? Wb1 : Wb2;
            int e = (idx < per) ? idx : idx - per;
            int k = e >> 12;
            int rem = e & 4095;
            int co = rem >> 6;
            int ci = rem & 63;
            dst[e] = f2bf(src[(k * C + ci) * C + co]);
        }
    } else if (bid < 224) {
        int b = bid - 216;
        int co = t & 63, seg = t >> 6;
        float acc = 0.f;
        for (int i = 0; i < 128; ++i) {
            int e = seg * 128 + i;
            float v = te[b * EMB + e];
            acc += silu_f(v) * Wt[e * C + co];
        }
        sh[t] = acc;
        __syncthreads();
        if (t < 64) tvec[b * C + t] = sh[t] + sh[t + 64] + sh[t + 128] + sh[t + 192] + bt[t];
    } else {
        for (int i = t; i < 520; i += 256) sh[i] = 0.f;
        __syncthreads();
        const int n0 = (bid - 224) * 256;
        const int c4 = t & 15, r = t >> 4;
        float s0 = 0.f, ss0 = 0.f, s1 = 0.f, ss1 = 0.f, c = 0.f;
        int cur = -1;
        for (int i = 0; i < 16; ++i) {
            int n = n0 + i * 16 + r;
            int b = batch_id[n];
            if (b != cur) {
                if (cur >= 0) {
                    int g0 = 2 * c4;
                    atomicAdd(&sh[(cur * NGROUP + g0) * 2 + 0], s0);
                    atomicAdd(&sh[(cur * NGROUP + g0) * 2 + 1], ss0);
                    atomicAdd(&sh[(cur * NGROUP + g0 + 1) * 2 + 0], s1);
                    atomicAdd(&sh[(cur * NGROUP + g0 + 1) * 2 + 1], ss1);
                    if (c4 == 0) atomicAdd(&sh[512 + cur], c);
                }
                cur = b; s0 = ss0 = s1 = ss1 = c = 0.f;
            }
            float4 v = *(const float4*)(x + (size_t)n * C + c4 * 4);
            s0 += v.x + v.y;  ss0 += v.x * v.x + v.y * v.y;
            s1 += v.z + v.w;  ss1 += v.z * v.z + v.w * v.w;
            c += 1.f;
        }
        {
            int g0 = 2 * c4;
            atomicAdd(&sh[(cur * NGROUP + g0) * 2 + 0], s0);
            atomicAdd(&sh[(cur * NGROUP + g0) * 2 + 1], ss0);
            atomicAdd(&sh[(cur * NGROUP + g0 + 1) * 2 + 0], s1);
            atomicAdd(&sh[(cur * NGROUP + g0 + 1) * 2 + 1], ss1);
            if (c4 == 0) atomicAdd(&sh[512 + cur], c);
        }
        __syncthreads();
        for (int i = t; i < 512; i += 256)
            if (sh[i] != 0.f) atomicAdd(&stats[i], sh[i]);
        if (t < 8 && sh[512 + t] != 0.f) atomicAdd(&cnt[t], sh[512 + t]);
    }
}

// ============ normalize + affine + SiLU -> bf16 (fp32 input), 8 ch/thread ============
__global__ void gn_apply_f32(const float* __restrict__ x, const int* __restrict__ batch_id,
                             const float* __restrict__ stats, const float* __restrict__ cnt,
                             const float* __restrict__ gamma, const float* __restrict__ beta,
                             u16* __restrict__ out) {
    int idx = blockIdx.x * 256 + threadIdx.x; // N*8
    int n = idx >> 3, seg = idx & 7;
    int b = batch_id[n];
    float denom = cnt[b] * 2.0f;
    float4 v0 = *(const float4*)(x + (size_t)n * C + seg * 8);
    float4 v1 = *(const float4*)(x + (size_t)n * C + seg * 8 + 4);
    float4 ga0 = *(const float4*)(gamma + seg * 8);
    float4 ga1 = *(const float4*)(gamma + seg * 8 + 4);
    float4 be0 = *(const float4*)(beta + seg * 8);
    float4 be1 = *(const float4*)(beta + seg * 8 + 4);
    float mn[4], rs[4];
#pragma unroll
    for (int p = 0; p < 4; ++p) {
        float2 st = *(const float2*)(stats + (b * NGROUP + seg * 4 + p) * 2);
        float mean = st.x / denom;
        float var = st.y / denom - mean * mean;
        mn[p] = mean;
        rs[p] = rsqrtf(var + GN_EPS);
    }
    float y0 = silu_f((v0.x - mn[0]) * rs[0] * ga0.x + be0.x);
    float y1 = silu_f((v0.y - mn[0]) * rs[0] * ga0.y + be0.y);
    float y2 = silu_f((v0.z - mn[1]) * rs[1] * ga0.z + be0.z);
    float y3 = silu_f((v0.w - mn[1]) * rs[1] * ga0.w + be0.w);
    float y4 = silu_f((v1.x - mn[2]) * rs[2] * ga1.x + be1.x);
    float y5 = silu_f((v1.y - mn[2]) * rs[2] * ga1.y + be1.y);
    float y6 = silu_f((v1.z - mn[3]) * rs[3] * ga1.z + be1.z);
    float y7 = silu_f((v1.w - mn[3]) * rs[3] * ga1.w + be1.w);
    uint4 o;
    o.x = pack2(y0, y1); o.y = pack2(y2, y3); o.z = pack2(y4, y5); o.w = pack2(y6, y7);
    *(uint4*)(out + (size_t)n * C + seg * 8) = o;
}

// ============ normalize + affine + SiLU -> bf16 (bf16 input), 8 ch/thread ============
__global__ void gn_apply_bf16(const u16* __restrict__ x, const int* __restrict__ batch_id,
                              const float* __restrict__ stats, const float* __restrict__ cnt,
                              const float* __restrict__ gamma, const float* __restrict__ beta,
                              u16* __restrict__ out) {
    int idx = blockIdx.x * 256 + threadIdx.x;
    int n = idx >> 3, seg = idx & 7;
    int b = batch_id[n];
    float denom = cnt[b] * 2.0f;
    uint4 u = *(const uint4*)(x + (size_t)n * C + seg * 8);
    float4 ga0 = *(const float4*)(gamma + seg * 8);
    float4 ga1 = *(const float4*)(gamma + seg * 8 + 4);
    float4 be0 = *(const float4*)(beta + seg * 8);
    float4 be1 = *(const float4*)(beta + seg * 8 + 4);
    float mn[4], rs[4];
#pragma unroll
    for (int p = 0; p < 4; ++p) {
        float2 st = *(const float2*)(stats + (b * NGROUP + seg * 4 + p) * 2);
        float mean = st.x / denom;
        float var = st.y / denom - mean * mean;
        mn[p] = mean;
        rs[p] = rsqrtf(var + GN_EPS);
    }
    float v0 = bf2f(u.x & 0xffff), v1 = bf2f(u.x >> 16);
    float v2 = bf2f(u.y & 0xffff), v3 = bf2f(u.y >> 16);
    float v4 = bf2f(u.z & 0xffff), v5 = bf2f(u.z >> 16);
    float v6 = bf2f(u.w & 0xffff), v7 = bf2f(u.w >> 16);
    float y0 = silu_f((v0 - mn[0]) * rs[0] * ga0.x + be0.x);
    float y1 = silu_f((v1 - mn[0]) * rs[0] * ga0.y + be0.y);
    float y2 = silu_f((v2 - mn[1]) * rs[1] * ga0.z + be0.z);
    float y3 = silu_f((v3 - mn[1]) * rs[1] * ga0.w + be0.w);
    float y4 = silu_f((v4 - mn[2]) * rs[2] * ga1.x + be1.x);
    float y5 = silu_f((v5 - mn[2]) * rs[2] * ga1.y + be1.y);
    float y6 = silu_f((v6 - mn[3]) * rs[3] * ga1.z + be1.z);
    float y7 = silu_f((v7 - mn[3]) * rs[3] * ga1.w + be1.w);
    uint4 o;
    o.x = pack2(y0, y1); o.y = pack2(y2, y3); o.z = pack2(y4, y5); o.w = pack2(y6, y7);
    *(uint4*)(out + (size_t)n * C + seg * 8) = o;
}

// ============ gather conv: A->regs w/ prefetch, W phase-resident in LDS ============
// Block 512 thr (8 waves), wave = 32 nodes x 64 co, block = 256 nodes, grid 512.
// W staged in 6 phases of 5/5/5/5/5/2 k-slices (40 KB); k-loop barrier-free.
// conv1: ADD_T + FUSE_STATS (gn2 stats from register-resident output; Wbuf reused as scratch).
template <bool ADD_T, bool FUSE_STATS, bool OUT_F32_RES>
__global__ __launch_bounds__(512, 4) void conv_kernel(
    const u16* __restrict__ act, const int* __restrict__ neigh,
    const u16* __restrict__ Wb, const float* __restrict__ bias,
    const float* __restrict__ tvec, const int* __restrict__ batch_id,
    const float* __restrict__ resid, void* __restrict__ outp,
    float* __restrict__ stats, float* __restrict__ cnt) {
    __shared__ u16 Wbuf[5 * 64 * 64]; // 40960 B
    float* shs = (float*)Wbuf;        // reused after k-loop for stats scratch

    const int tid = threadIdx.x;
    const int w = tid >> 6, lane = tid & 63;
    const int q = lane >> 4, m = lane & 15;
    const int n0 = blockIdx.x * 256;
    const int nw = n0 + w * 32;

    const int* nrow0 = neigh + (size_t)(nw + m) * KNB;
    const int* nrow1 = neigh + (size_t)(nw + 16 + m) * KNB;

    f32x4 acc[2][4] = {};
    bf16x8 aC[2][2];
    int offn0, offn1;

    {
        int o0 = nrow0[0] * C, o1 = nrow1[0] * C;
        aC[0][0] = *(const bf16x8*)(act + o0 + q * 8);
        aC[0][1] = *(const bf16x8*)(act + o0 + 32 + q * 8);
        aC[1][0] = *(const bf16x8*)(act + o1 + q * 8);
        aC[1][1] = *(const bf16x8*)(act + o1 + 32 + q * 8);
        offn0 = nrow0[1] * C;
        offn1 = nrow1[1] * C;
    }

    for (int phase = 0; phase < 6; ++phase) {
        const int k0 = phase * 5;
        const int nk = (phase == 5) ? 2 : 5;
        if (phase) __syncthreads(); // prior phase's Wbuf reads done
        const int total = nk * 512;
#pragma unroll
        for (int it = 0; it < 5; ++it) {
            int cb = it * 512 + w * 64;
            if (cb < total) {
                int c = cb + lane;
                int r = c >> 3;
                int pos = c & 7;
                int srcc = pos ^ (r & 7);
                gload_lds16(Wb + (((k0 << 6) + r) << 6) + (srcc << 3), Wbuf + cb * 8);
            }
        }
        __syncthreads(); // W visible

        for (int sI = 0; sI < nk; ++sI) {
            const int k = k0 + sI;
            const int kn = k + 1;
            bf16x8 an[2][2];
            if (kn < KNB) {
                an[0][0] = *(const bf16x8*)(act + offn0 + q * 8);
                an[0][1] = *(const bf16x8*)(act + offn0 + 32 + q * 8);
                an[1][0] = *(const bf16x8*)(act + offn1 + q * 8);
                an[1][1] = *(const bf16x8*)(act + offn1 + 32 + q * 8);
            }
            if (kn + 1 < KNB) {
                offn0 = nrow0[kn + 1] * C;
                offn1 = nrow1[kn + 1] * C;
            }
            const u16* wsl = Wbuf + sI * 4096;
#pragma unroll
            for (int kk = 0; kk < 2; ++kk) {
#pragma unroll
                for (int j = 0; j < 4; ++j) {
                    const int co = j * 16 + m;
                    const int lc = kk * 4 + q;
                    bf16x8 b = *(const bf16x8*)(wsl + (co << 6) + ((lc ^ (co & 7)) << 3));
                    acc[0][j] = __builtin_amdgcn_mfma_f32_16x16x32_bf16(aC[0][kk], b, acc[0][j], 0, 0, 0);
                    acc[1][j] = __builtin_amdgcn_mfma_f32_16x16x32_bf16(aC[1][kk], b, acc[1][j], 0, 0, 0);
                }
            }
            if (kn < KNB) {
                aC[0][0] = an[0][0]; aC[0][1] = an[0][1];
                aC[1][0] = an[1][0]; aC[1][1] = an[1][1];
            }
        }
    }

    // ---- epilogue: bias (+temb), store; D: col=m (co j*16+m), row=q*4+reg ----
    float bs[4];
#pragma unroll
    for (int j = 0; j < 4; ++j) bs[j] = bias[j * 16 + m];

#pragma unroll
    for (int s = 0; s < 2; ++s) {
#pragma unroll
        for (int reg = 0; reg < 4; ++reg) {
            const int n = nw + s * 16 + q * 4 + reg;
            int b = 0;
            if (ADD_T) b = batch_id[n];
#pragma unroll
            for (int j = 0; j < 4; ++j) {
                const int co = j * 16 + m;
                float v = acc[s][j][reg] + bs[j];
                if (ADD_T) v += tvec[b * C + co];
                acc[s][j][reg] = v;
                if (OUT_F32_RES) {
                    ((float*)outp)[(size_t)n * C + co] = v + resid[(size_t)n * C + co];
                } else {
                    ((u16*)outp)[(size_t)n * C + co] = f2bf(v);
                }
            }
        }
    }

    if (FUSE_STATS) {
        __syncthreads(); // all waves done reading Wbuf -> safe to reuse as shs
        for (int i = tid; i < 520; i += 512) shs[i] = 0.f;
        __syncthreads();
        const int blo = batch_id[nw], bhi = batch_id[nw + 31];
        if (blo == bhi) {
#pragma unroll
            for (int j = 0; j < 4; ++j) {
                float s = 0.f, ss = 0.f;
#pragma unroll
                for (int sq = 0; sq < 2; ++sq)
#pragma unroll
                    for (int reg = 0; reg < 4; ++reg) {
                        float v = acc[sq][j][reg];
                        s += v; ss += v * v;
                    }
                s += __shfl_xor(s, 16, 64);  ss += __shfl_xor(ss, 16, 64);
                s += __shfl_xor(s, 32, 64);  ss += __shfl_xor(ss, 32, 64);
                s += __shfl_xor(s, 1, 64);   ss += __shfl_xor(ss, 1, 64);
                if (q == 0 && (m & 1) == 0) {
                    int g = (j * 16 + m) >> 1;
                    atomicAdd(&shs[(blo * NGROUP + g) * 2 + 0], s);
                    atomicAdd(&shs[(blo * NGROUP + g) * 2 + 1], ss);
                }
            }
        } else {
#pragma unroll
            for (int sq = 0; sq < 2; ++sq)
#pragma unroll
                for (int reg = 0; reg < 4; ++reg) {
                    int b = batch_id[nw + sq * 16 + q * 4 + reg];
#pragma unroll
                    for (int j = 0; j < 4; ++j) {
                        int g = (j * 16 + m) >> 1;
                        float v = acc[sq][j][reg];
                        atomicAdd(&shs[(b * NGROUP + g) * 2 + 0], v);
                        atomicAdd(&shs[(b * NGROUP + g) * 2 + 1], v * v);
                    }
                }
        }
        if (tid < 256) atomicAdd(&shs[512 + batch_id[n0 + tid]], 1.0f);
        __syncthreads();
        if (tid < 512 && shs[tid] != 0.f) atomicAdd(&stats[tid], shs[tid]);
        if (tid < 8 && shs[512 + tid] != 0.f) atomicAdd(&cnt[tid], shs[512 + tid]);
    }
}

extern "C" void kernel_launch(void* const* d_in, const int* in_sizes, int n_in,
                              void* d_out, int out_size, void* d_ws, size_t ws_size,
                              hipStream_t stream) {
    const float* x        = (const float*)d_in[0];
    const float* time_emb = (const float*)d_in[1];
    const int*   batch_id = (const int*)d_in[2];
    const int*   neigh    = (const int*)d_in[3];
    const float* g1       = (const float*)d_in[4];
    const float* be1      = (const float*)d_in[5];
    const float* W1       = (const float*)d_in[6];
    const float* b1       = (const float*)d_in[7];
    const float* Wt       = (const float*)d_in[8];
    const float* bt       = (const float*)d_in[9];
    const float* g2       = (const float*)d_in[10];
    const float* be2      = (const float*)d_in[11];
    const float* W2       = (const float*)d_in[12];
    const float* b2       = (const float*)d_in[13];

    char* ws = (char*)d_ws;
    u16*   h1     = (u16*)(ws + 0);            // 16 MB
    u16*   h2     = (u16*)(ws + 16777216);     // 16 MB
    u16*   h3     = (u16*)(ws + 33554432);     // 16 MB
    u16*   Wb1    = (u16*)(ws + 50331648);     // 221184 B
    u16*   Wb2    = (u16*)(ws + 50552832);     // 221184 B
    float* tvec   = (float*)(ws + 50774016);   // 2048 B
    float* stats1 = (float*)(ws + 50776064);   // 512 f
    float* cnt1   = stats1 + 512;              // 8 f
    float* stats2 = cnt1 + 8;                  // 512 f
    float* cnt2   = stats2 + 512;              // 8 f

    hipMemsetAsync(ws + 50776064, 0, 1040 * sizeof(float), stream);
    setup_kernel<<<736, 256, 0, stream>>>(W1, W2, Wb1, Wb2, time_emb, Wt, bt, tvec,
                                          x, batch_id, stats1, cnt1);
    gn_apply_f32<<<4096, 256, 0, stream>>>(x, batch_id, stats1, cnt1, g1, be1, h1);
    conv_kernel<true, true, false><<<512, 512, 0, stream>>>(
        h1, neigh, Wb1, b1, tvec, batch_id, nullptr, (void*)h2, stats2, cnt2);
    gn_apply_bf16<<<4096, 256, 0, stream>>>(h2, batch_id, stats2, cnt2, g2, be2, h3);
    conv_kernel<false, false, true><<<512, 512, 0, stream>>>(
        h3, neigh, Wb2, b2, nullptr, nullptr, x, (void*)d_out, nullptr, nullptr);
}